// Round 15
// baseline (55.623 us; speedup 1.0000x reference)
//
#include <hip/hip_runtime.h>
#include <hip/hip_bf16.h>

// GraphAttentionLayer collapse: out[b,i,o] = (S_mask[b,i,o] < 0) ? 1 : 0,
// S_mask = sum_{adj[i,j]==0} hW[b,j,o]  (|9e15*S_mask| >> |softmax term| => sigmoid saturates).
// Exact i8 MFMA path:
//   q = rint(hW*2^16) = d0 + 256*d1 + 65536*d2, balanced digits in [-128,127] (exact i8).
//   mask bit 0/1 exact i8; i32 MFMA accumulation exact.
//   S = c0 + 256*c1 + 65536*c2 (f64, exact integers). |S| > 2048 => sign reliable;
//   else exact f64 recompute in-block.
// Round-15: pack v3 (wave-uniform row -> every instr covers contiguous 4KB; R9-verified
// LDS transpose phase-2 unchanged). hwrepack v7 (8 rows/thread, W+h both f32 in LDS,
// zero VMEM in k-loop, low VGPR -> 512 blocks = exactly 2/CU single round). gemm frozen.

#define GN 4096
#define GB 4
#define FIN 128
#define FOUT 64

typedef int i32x4 __attribute__((ext_vector_type(4)));
typedef unsigned int uint32x4 __attribute__((ext_vector_type(4)));
typedef float f32x4 __attribute__((ext_vector_type(4)));

// ---- kernel 1: adj -> transposed bitmask tmask[(rt*64+s)*64 + l] (u64), coalesced ----
// bit (r*16+jj) of tmask[rt*64+s][l] = (adj[rt*64 + r*16 + (l&15)][s*64 + (l>>4)*16 + jj] == 0)
// Phase 1: pass p<16, row = p*4 + (t>>6) (wave-uniform), j16 = t&63 = lane ->
// wave instruction = 64 lanes x 64B = contiguous 4KB. m16[row][j16] = 16-bit mask.
// Phase 2: byte-identical to R9-verified transpose.
__global__ __launch_bounds__(256) void pack_kernel(const int* __restrict__ adj,
                                                   unsigned long long* __restrict__ tmask) {
    __shared__ unsigned short m16[64][68];
    const int t = threadIdx.x;
    const int rt = (int)blockIdx.x >> 2, cp = (int)blockIdx.x & 3;
    const int wrow = t >> 6;      // wave-uniform row offset
    const int j16 = t & 63;       // lane

#pragma unroll
    for (int p = 0; p < 16; ++p) {
        const int row = p * 4 + wrow;
        const i32x4* src = (const i32x4*)(adj + (size_t)(rt * 64 + row) * GN
                                          + cp * 1024 + j16 * 16);
        unsigned int b16 = 0;
#pragma unroll
        for (int q = 0; q < 4; ++q) {
            i32x4 v = src[q];
            b16 |= (v.x == 0 ? 1u : 0u) << (q * 4);
            b16 |= (v.y == 0 ? 2u : 0u) << (q * 4);
            b16 |= (v.z == 0 ? 4u : 0u) << (q * 4);
            b16 |= (v.w == 0 ? 8u : 0u) << (q * 4);
        }
        m16[row][j16] = (unsigned short)b16;
    }
    __syncthreads();

    // phase 2 (verified R9): s = cp*16 + sloc
#pragma unroll
    for (int it = 0; it < 4; ++it) {
        const int idx = it * 256 + t;
        const int sloc = idx >> 6, l = idx & 63;
        const int row16 = l & 15, g = l >> 4;
        unsigned long long res = 0ull;
#pragma unroll
        for (int r = 0; r < 4; ++r)
            res |= (unsigned long long)m16[r * 16 + row16][sloc * 4 + g] << (r * 16);
        tmask[((size_t)rt * 64 + cp * 16 + sloc) * 64 + l] = res;
    }
}

// ---- kernel 2: hW = h @ W (f64) + digit planes, v7 (8 rows/thread, LDS operands) ----
// 512 blocks x 256 thr; block = 32 rows (b = bx>>7, rows (bx&127)*32..+31).
// Thread (a = t>>6, o = t&63): rows row0..row0+7, row0 = (bx&127)*32 + a*8.
// k-loop: W from LDS f32 (2-way alias = free), h via b128 broadcast (wave-uniform addr).
// Zero VMEM in loop. Digits: thread owns 2 q4 units -> builds 6 plane words alone.
// Bp layout (verified R7..R14): Bp[(b*64+p)*12288 + pl*4096 + cg*1024 + g*256 + col16*16 + qr*4].
__global__ __launch_bounds__(256) void hwrepack_kernel(const float* __restrict__ h,
                                                       const float* __restrict__ W,
                                                       double* __restrict__ hW,
                                                       unsigned char* __restrict__ Bp) {
    __shared__ float Wl[FIN][FOUT];     // 32 KB
    __shared__ float hsf[32][FIN];      // 16 KB
    const int t = threadIdx.x;
    const int o = t & 63, a = t >> 6;
    const int bx = (int)blockIdx.x;
    const int b = bx >> 7, rq = bx & 127;

    // stage W -> LDS f32 (coalesced, 8 f32x4/thread)
    {
        const f32x4* Wv = (const f32x4*)W;
        f32x4* Wlv = (f32x4*)&Wl[0][0];
#pragma unroll
        for (int c = 0; c < 8; ++c)
            Wlv[c * 256 + t] = Wv[c * 256 + t];
    }
    // stage 32 rows of h -> LDS f32 (4096 f32 = 1024 f32x4; 4 per thread)
    {
        const f32x4* src = (const f32x4*)(h + ((size_t)b * GN + rq * 32) * FIN);
        f32x4* dst = (f32x4*)&hsf[0][0];
#pragma unroll
        for (int c = 0; c < 4; ++c)
            dst[c * 256 + t] = src[c * 256 + t];
    }
    __syncthreads();

    const int row0 = rq * 32 + a * 8;
    double ac[8];
#pragma unroll
    for (int rr = 0; rr < 8; ++rr) ac[rr] = 0.0;

#pragma unroll
    for (int k4 = 0; k4 < 32; ++k4) {
        f32x4 hv[8];
#pragma unroll
        for (int rr = 0; rr < 8; ++rr)
            hv[rr] = *(const f32x4*)&hsf[a * 8 + rr][k4 * 4];   // b128 broadcast
#pragma unroll
        for (int j = 0; j < 4; ++j) {
            double wd = (double)Wl[k4 * 4 + j][o];              // 2-way alias, free
#pragma unroll
            for (int rr = 0; rr < 8; ++rr)
                ac[rr] = fma((double)hv[rr][j], wd, ac[rr]);
        }
    }

    double* hwp = hW + ((size_t)b * GN + row0) * FOUT + o;
#pragma unroll
    for (int rr = 0; rr < 8; ++rr)
        hwp[(size_t)rr * FOUT] = ac[rr];

    // digits: two q4 units (q4 = row0/4 + u)
#pragma unroll
    for (int u = 0; u < 2; ++u) {
        unsigned int w0 = 0, w1 = 0, w2 = 0;
#pragma unroll
        for (int rr = 0; rr < 4; ++rr) {
            int qi = (int)llrint(ac[u * 4 + rr] * 65536.0);
            int d0 = ((qi + 128) & 255) - 128; qi = (qi - d0) >> 8;
            int d1 = ((qi + 128) & 255) - 128; qi = (qi - d1) >> 8;  // qi now = d2
            w0 |= (unsigned int)(d0 & 255) << (rr * 8);
            w1 |= (unsigned int)(d1 & 255) << (rr * 8);
            w2 |= (unsigned int)(qi & 255) << (rr * 8);
        }
        const int q4 = (row0 >> 2) + u;
        const int p = q4 >> 4, g = (q4 >> 2) & 3, qr = q4 & 3;
        const int cg = o >> 4, col16 = o & 15;
        unsigned char* dst = Bp + ((size_t)b * 64 + p) * 12288
                           + cg * 1024 + g * 256 + col16 * 16 + qr * 4;
        *(unsigned int*)(dst)        = w0;
        *(unsigned int*)(dst + 4096) = w1;
        *(unsigned int*)(dst + 8192) = w2;
    }
}

// ---- kernel 3: exact i8-MFMA masked-sum GEMM, depth-4 register pipeline (R10, frozen) ----
__global__ __launch_bounds__(512, 1) void gemm_kernel(const unsigned char* __restrict__ Bp,
                                                      const unsigned long long* __restrict__ tmask,
                                                      const double* __restrict__ hW,
                                                      float* __restrict__ out) {
    __shared__ __align__(16) unsigned char lds[49152];   // kg-merge
    __shared__ unsigned int nflag;
    __shared__ unsigned int flagbuf[128];
    __shared__ double fred[8];

    const int tid = threadIdx.x, lane = tid & 63, wv = tid >> 6;
    const int cg = wv & 3, kg = wv >> 2;
    const int rt = (int)blockIdx.x >> 2, b = (int)blockIdx.x & 3;
    if (tid == 0) nflag = 0;

    const unsigned char* bptr = Bp + (size_t)b * 786432 + kg * 12288 + cg * 1024 + lane * 16;
    const unsigned long long* mptr = tmask + (size_t)rt * 4096 + kg * 64 + lane;

    i32x4 acc[4][3];
#pragma unroll
    for (int r = 0; r < 4; ++r)
#pragma unroll
        for (int pl = 0; pl < 3; ++pl) {
            i32x4 z = {0, 0, 0, 0};
            acc[r][pl] = z;
        }

#define DECLSET(S) i32x4 b##S##0, b##S##1, b##S##2; unsigned long long m##S;
#define LOADSET(S, T) { const unsigned char* g_ = bptr + (size_t)(T) * 24576;          \
        b##S##0 = *(const i32x4*)(g_);                                                 \
        b##S##1 = *(const i32x4*)(g_ + 4096);                                          \
        b##S##2 = *(const i32x4*)(g_ + 8192);                                          \
        m##S = mptr[(size_t)(T) * 128]; }

    DECLSET(A) DECLSET(B) DECLSET(C) DECLSET(D)
    LOADSET(A, 0) LOADSET(B, 1) LOADSET(C, 2) LOADSET(D, 3)

    auto dostep = [&](unsigned long long mw, i32x4 v0, i32x4 v1, i32x4 v2) {
        const unsigned int mlo = (unsigned int)mw, mhi = (unsigned int)(mw >> 32);
#pragma unroll
        for (int r = 0; r < 4; ++r) {
            unsigned int half = (r >> 1) ? mhi : mlo;
            unsigned int w16 = (r & 1) ? (half >> 16) : (half & 0xFFFFu);
            uint32x4 u;
#pragma unroll
            for (int q = 0; q < 4; ++q)
                u[q] = (((w16 >> (4 * q)) & 0xFu) * 0x00204081u) & 0x01010101u;
            i32x4 af = __builtin_bit_cast(i32x4, u);
            acc[r][0] = __builtin_amdgcn_mfma_i32_16x16x64_i8(af, v0, acc[r][0], 0, 0, 0);
            acc[r][1] = __builtin_amdgcn_mfma_i32_16x16x64_i8(af, v1, acc[r][1], 0, 0, 0);
            acc[r][2] = __builtin_amdgcn_mfma_i32_16x16x64_i8(af, v2, acc[r][2], 0, 0, 0);
        }
    };

    for (int T = 0; T < 32; T += 4) {
        dostep(mA, bA0, bA1, bA2);
        if (T + 4 < 32) LOADSET(A, T + 4)
        dostep(mB, bB0, bB1, bB2);
        if (T + 5 < 32) LOADSET(B, T + 5)
        dostep(mC, bC0, bC1, bC2);
        if (T + 6 < 32) LOADSET(C, T + 6)
        dostep(mD, bD0, bD1, bD2);
        if (T + 7 < 32) LOADSET(D, T + 7)
    }
#undef DECLSET
#undef LOADSET

    // merge kg=1 partials into kg=0 via LDS
    __syncthreads();
    if (kg == 1) {
        unsigned char* dst = lds + cg * 12288 + lane * 192;
#pragma unroll
        for (int r = 0; r < 4; ++r)
#pragma unroll
            for (int pl = 0; pl < 3; ++pl)
                *(i32x4*)(dst + (r * 3 + pl) * 16) = acc[r][pl];
    }
    __syncthreads();
    if (kg == 0) {
        const unsigned char* s2 = lds + cg * 12288 + lane * 192;
#pragma unroll
        for (int r = 0; r < 4; ++r)
#pragma unroll
            for (int pl = 0; pl < 3; ++pl) {
                i32x4 v = *(const i32x4*)(s2 + (r * 3 + pl) * 16);
#pragma unroll
                for (int q = 0; q < 4; ++q) acc[r][pl][q] += v[q];
            }

        const int o = cg * 16 + (lane & 15);
#pragma unroll
        for (int r = 0; r < 4; ++r) {
#pragma unroll
            for (int q = 0; q < 4; ++q) {
                double S = (double)acc[r][0][q] + 256.0 * (double)acc[r][1][q]
                         + 65536.0 * (double)acc[r][2][q];     // exact integer
                int i = rt * 64 + r * 16 + (lane >> 4) * 4 + q;  // C/D row map (m89)
                size_t oi = ((size_t)b * GN + i) * FOUT + o;
                out[oi] = S < 0.0 ? 1.0f : 0.0f;
                if (fabs(S) <= 2048.0) {
                    unsigned int idx = atomicAdd(&nflag, 1u);
                    if (idx < 128) flagbuf[idx] = ((unsigned int)i << 6) | (unsigned int)o;
                }
            }
        }
    }

    // ---- in-block exact fixup (expected ~0.2 items/block) ----
    __syncthreads();
    unsigned int nf = nflag;
    if (nf > 128) nf = 128;
    for (unsigned int f = 0; f < nf; ++f) {
        unsigned int e = flagbuf[f];
        int o = e & 63;
        int i = (int)(e >> 6);
        int row16 = i & 15, r = (i >> 4) & 3;
        int s = tid >> 3, lg = (tid >> 1) & 3, hf = tid & 1;
        unsigned long long w = tmask[((size_t)rt * 64 + s) * 64 + (lg * 16 + row16)];
        double ps = 0.0;
        const double* hwc = hW + ((size_t)b * GN + s * 64 + lg * 16) * FOUT + o;
#pragma unroll
        for (int jj = hf * 8; jj < hf * 8 + 8; ++jj) {
            if ((w >> (r * 16 + jj)) & 1ull)
                ps += hwc[(size_t)jj * FOUT];
        }
#pragma unroll
        for (int d = 32; d >= 1; d >>= 1) ps += __shfl_down(ps, d, 64);
        if (lane == 0) fred[wv] = ps;
        __syncthreads();
        if (tid == 0) {
            double tot = ((fred[0] + fred[1]) + (fred[2] + fred[3]))
                       + ((fred[4] + fred[5]) + (fred[6] + fred[7]));
            out[((size_t)b * GN + i) * FOUT + o] = tot < 0.0 ? 1.0f : 0.0f;
        }
        __syncthreads();
    }
}

extern "C" void kernel_launch(void* const* d_in, const int* in_sizes, int n_in,
                              void* d_out, int out_size, void* d_ws, size_t ws_size,
                              hipStream_t stream) {
    const float* h   = (const float*)d_in[0];   // [4,4096,128]
    const int*   adj = (const int*)d_in[1];     // [4096,4096]
    const float* W   = (const float*)d_in[2];   // [128,64]
    float* out = (float*)d_out;                 // [4,4096,64] f32

    char* ws = (char*)d_ws;
    double* hW                = (double*)ws;                          // 8 MB @ 0
    unsigned char* Bp         = (unsigned char*)(ws + 8388608);       // 3 MB @ 8M
    unsigned long long* tmask = (unsigned long long*)(ws + 12582912); // 2 MB @ 12M

    pack_kernel<<<256, 256, 0, stream>>>(adj, tmask);
    hwrepack_kernel<<<512, 256, 0, stream>>>(h, W, hW, Bp);
    gemm_kernel<<<256, 512, 0, stream>>>(Bp, tmask, hW, out);
}

// Round 17
// 55.464 us; speedup vs baseline: 1.0029x; 1.0029x over previous
//
#include <hip/hip_runtime.h>
#include <hip/hip_bf16.h>

// GraphAttentionLayer collapse: out[b,i,o] = (S_mask[b,i,o] < 0) ? 1 : 0,
// S_mask = sum_{adj[i,j]==0} hW[b,j,o]  (|9e15*S_mask| >> |softmax term| => sigmoid saturates).
// Exact i8 MFMA path:
//   q = rint(hW*2^16) = d0 + 256*d1 + 65536*d2, balanced digits in [-128,127] (exact i8).
//   mask bit 0/1 exact i8; i32 MFMA accumulation exact.
//   S = c0 + 256*c1 + 65536*c2 (f64, exact integers). |S| > 2048 => sign reliable;
//   else exact f64 recompute in-block.
// ROUND-16 BUG FIX: pack v4's phase-2 kept the 256-thread loop count (it<4) after
// moving to 1024 threads -> sloc ran 0..63 instead of 0..15, clobbering OTHER blocks'
// tmask ranges. With 1024 threads phase 2 is ONE pass: sloc = t>>6 in [0,16).
// hwrepack v9 (scalar-pipe h) and gemm (R10 depth-4) unchanged from R16.

#define GN 4096
#define GB 4
#define FIN 128
#define FOUT 64

typedef int i32x4 __attribute__((ext_vector_type(4)));
typedef unsigned int uint32x4 __attribute__((ext_vector_type(4)));
typedef float f32x4 __attribute__((ext_vector_type(4)));

// ---- kernel 1: adj -> transposed bitmask tmask[(rt*64+s)*64 + l] (u64), coalesced ----
// bit (r*16+jj) of tmask[rt*64+s][l] = (adj[rt*64 + r*16 + (l&15)][s*64 + (l>>4)*16 + jj] == 0)
// 1024 threads: phase 1 pass p<4, row = p*16 + (t>>6) (wave-uniform), j16 = t&63 ->
// wave instr = 64 lanes x 64B contiguous. Phase 2: ONE pass, sloc = t>>6 (0..15).
__global__ __launch_bounds__(1024) void pack_kernel(const int* __restrict__ adj,
                                                    unsigned long long* __restrict__ tmask) {
    __shared__ unsigned short m16[64][68];
    const int t = threadIdx.x;
    const int rt = (int)blockIdx.x >> 2, cp = (int)blockIdx.x & 3;
    const int wrow = t >> 6;      // 0..15, wave-uniform
    const int j16 = t & 63;       // lane

#pragma unroll
    for (int p = 0; p < 4; ++p) {
        const int row = p * 16 + wrow;
        const i32x4* src = (const i32x4*)(adj + (size_t)(rt * 64 + row) * GN
                                          + cp * 1024 + j16 * 16);
        unsigned int b16 = 0;
#pragma unroll
        for (int q = 0; q < 4; ++q) {
            i32x4 v = src[q];
            b16 |= (v.x == 0 ? 1u : 0u) << (q * 4);
            b16 |= (v.y == 0 ? 2u : 0u) << (q * 4);
            b16 |= (v.z == 0 ? 4u : 0u) << (q * 4);
            b16 |= (v.w == 0 ? 8u : 0u) << (q * 4);
        }
        m16[row][j16] = (unsigned short)b16;
    }
    __syncthreads();

    // phase 2 (R9-verified math, rescaled for 1024 thr): 1024 words/block, 1 each
    {
        const int sloc = t >> 6, l = t & 63;      // sloc in [0,16)
        const int row16 = l & 15, g = l >> 4;
        unsigned long long res = 0ull;
#pragma unroll
        for (int r = 0; r < 4; ++r)
            res |= (unsigned long long)m16[r * 16 + row16][sloc * 4 + g] << (r * 16);
        tmask[((size_t)rt * 64 + cp * 16 + sloc) * 64 + l] = res;
    }
}

// ---- kernel 2: hW = h @ W (f64) + digit planes, v9 (scalar-pipe h) ----
// 1024 blocks x 256 thr; block = 16 rows (b = bx>>8, rows (bx&255)*16..+15).
// Thread (a = t>>6, o = t&63): rows row0..row0+3, row0 = (bx&255)*16 + a*4.
// a forced into SGPR via readfirstlane -> h base provably wave-uniform -> s_load.
// W from LDS f32 b32 (2-way alias = free). Digit layout verified R7..R15.
__global__ __launch_bounds__(256) void hwrepack_kernel(const float* __restrict__ h,
                                                       const float* __restrict__ W,
                                                       double* __restrict__ hW,
                                                       unsigned char* __restrict__ Bp) {
    __shared__ float Wl[FIN][FOUT];     // 32 KB
    const int t = threadIdx.x;
    const int o = t & 63;
    const int a = __builtin_amdgcn_readfirstlane(t >> 6);   // wave-uniform -> SGPR
    const int bx = (int)blockIdx.x;
    const int b = bx >> 8, rq = bx & 255;

    // stage W -> LDS f32 (coalesced, 8 f32x4/thread)
    {
        const f32x4* Wv = (const f32x4*)W;
        f32x4* Wlv = (f32x4*)&Wl[0][0];
#pragma unroll
        for (int c = 0; c < 8; ++c)
            Wlv[c * 256 + t] = Wv[c * 256 + t];
    }
    __syncthreads();

    const int row0 = rq * 16 + a * 4;
    const float* h0 = h + ((size_t)b * GN + row0) * FIN;    // scalar base
    double ac0 = 0, ac1 = 0, ac2 = 0, ac3 = 0;
#pragma unroll 16
    for (int k = 0; k < FIN; ++k) {
        double wd = (double)Wl[k][o];           // LDS b32, 2-way alias (free)
        ac0 = fma((double)h0[k],           wd, ac0);   // s_load-sourced operands
        ac1 = fma((double)h0[k + FIN],     wd, ac1);
        ac2 = fma((double)h0[k + 2 * FIN], wd, ac2);
        ac3 = fma((double)h0[k + 3 * FIN], wd, ac3);
    }

    double* hwp = hW + ((size_t)b * GN + row0) * FOUT + o;
    hwp[0]        = ac0;
    hwp[FOUT]     = ac1;
    hwp[2 * FOUT] = ac2;
    hwp[3 * FOUT] = ac3;

    // digits for the 4 rows -> 3 plane words (verified R13/R14 mapping)
    unsigned int w0 = 0, w1 = 0, w2 = 0;
    double accs[4] = {ac0, ac1, ac2, ac3};
#pragma unroll
    for (int rr = 0; rr < 4; ++rr) {
        int qi = (int)llrint(accs[rr] * 65536.0);
        int d0 = ((qi + 128) & 255) - 128; qi = (qi - d0) >> 8;
        int d1 = ((qi + 128) & 255) - 128; qi = (qi - d1) >> 8;  // qi now = d2
        w0 |= (unsigned int)(d0 & 255) << (rr * 8);
        w1 |= (unsigned int)(d1 & 255) << (rr * 8);
        w2 |= (unsigned int)(qi & 255) << (rr * 8);
    }
    const int q4 = rq * 4 + a;                // row0 == q4*4
    const int p = q4 >> 4, g = (q4 >> 2) & 3, qr = q4 & 3;
    const int cg = o >> 4, col16 = o & 15;
    unsigned char* dst = Bp + ((size_t)b * 64 + p) * 12288
                       + cg * 1024 + g * 256 + col16 * 16 + qr * 4;
    *(unsigned int*)(dst)        = w0;
    *(unsigned int*)(dst + 4096) = w1;
    *(unsigned int*)(dst + 8192) = w2;
}

// ---- kernel 3: exact i8-MFMA masked-sum GEMM, depth-4 register pipeline (R10, frozen) ----
__global__ __launch_bounds__(512, 1) void gemm_kernel(const unsigned char* __restrict__ Bp,
                                                      const unsigned long long* __restrict__ tmask,
                                                      const double* __restrict__ hW,
                                                      float* __restrict__ out) {
    __shared__ __align__(16) unsigned char lds[49152];   // kg-merge
    __shared__ unsigned int nflag;
    __shared__ unsigned int flagbuf[128];
    __shared__ double fred[8];

    const int tid = threadIdx.x, lane = tid & 63, wv = tid >> 6;
    const int cg = wv & 3, kg = wv >> 2;
    const int rt = (int)blockIdx.x >> 2, b = (int)blockIdx.x & 3;
    if (tid == 0) nflag = 0;

    const unsigned char* bptr = Bp + (size_t)b * 786432 + kg * 12288 + cg * 1024 + lane * 16;
    const unsigned long long* mptr = tmask + (size_t)rt * 4096 + kg * 64 + lane;

    i32x4 acc[4][3];
#pragma unroll
    for (int r = 0; r < 4; ++r)
#pragma unroll
        for (int pl = 0; pl < 3; ++pl) {
            i32x4 z = {0, 0, 0, 0};
            acc[r][pl] = z;
        }

#define DECLSET(S) i32x4 b##S##0, b##S##1, b##S##2; unsigned long long m##S;
#define LOADSET(S, T) { const unsigned char* g_ = bptr + (size_t)(T) * 24576;          \
        b##S##0 = *(const i32x4*)(g_);                                                 \
        b##S##1 = *(const i32x4*)(g_ + 4096);                                          \
        b##S##2 = *(const i32x4*)(g_ + 8192);                                          \
        m##S = mptr[(size_t)(T) * 128]; }

    DECLSET(A) DECLSET(B) DECLSET(C) DECLSET(D)
    LOADSET(A, 0) LOADSET(B, 1) LOADSET(C, 2) LOADSET(D, 3)

    auto dostep = [&](unsigned long long mw, i32x4 v0, i32x4 v1, i32x4 v2) {
        const unsigned int mlo = (unsigned int)mw, mhi = (unsigned int)(mw >> 32);
#pragma unroll
        for (int r = 0; r < 4; ++r) {
            unsigned int half = (r >> 1) ? mhi : mlo;
            unsigned int w16 = (r & 1) ? (half >> 16) : (half & 0xFFFFu);
            uint32x4 u;
#pragma unroll
            for (int q = 0; q < 4; ++q)
                u[q] = (((w16 >> (4 * q)) & 0xFu) * 0x00204081u) & 0x01010101u;
            i32x4 af = __builtin_bit_cast(i32x4, u);
            acc[r][0] = __builtin_amdgcn_mfma_i32_16x16x64_i8(af, v0, acc[r][0], 0, 0, 0);
            acc[r][1] = __builtin_amdgcn_mfma_i32_16x16x64_i8(af, v1, acc[r][1], 0, 0, 0);
            acc[r][2] = __builtin_amdgcn_mfma_i32_16x16x64_i8(af, v2, acc[r][2], 0, 0, 0);
        }
    };

    for (int T = 0; T < 32; T += 4) {
        dostep(mA, bA0, bA1, bA2);
        if (T + 4 < 32) LOADSET(A, T + 4)
        dostep(mB, bB0, bB1, bB2);
        if (T + 5 < 32) LOADSET(B, T + 5)
        dostep(mC, bC0, bC1, bC2);
        if (T + 6 < 32) LOADSET(C, T + 6)
        dostep(mD, bD0, bD1, bD2);
        if (T + 7 < 32) LOADSET(D, T + 7)
    }
#undef DECLSET
#undef LOADSET

    // merge kg=1 partials into kg=0 via LDS
    __syncthreads();
    if (kg == 1) {
        unsigned char* dst = lds + cg * 12288 + lane * 192;
#pragma unroll
        for (int r = 0; r < 4; ++r)
#pragma unroll
            for (int pl = 0; pl < 3; ++pl)
                *(i32x4*)(dst + (r * 3 + pl) * 16) = acc[r][pl];
    }
    __syncthreads();
    if (kg == 0) {
        const unsigned char* s2 = lds + cg * 12288 + lane * 192;
#pragma unroll
        for (int r = 0; r < 4; ++r)
#pragma unroll
            for (int pl = 0; pl < 3; ++pl) {
                i32x4 v = *(const i32x4*)(s2 + (r * 3 + pl) * 16);
#pragma unroll
                for (int q = 0; q < 4; ++q) acc[r][pl][q] += v[q];
            }

        const int o = cg * 16 + (lane & 15);
#pragma unroll
        for (int r = 0; r < 4; ++r) {
#pragma unroll
            for (int q = 0; q < 4; ++q) {
                double S = (double)acc[r][0][q] + 256.0 * (double)acc[r][1][q]
                         + 65536.0 * (double)acc[r][2][q];     // exact integer
                int i = rt * 64 + r * 16 + (lane >> 4) * 4 + q;  // C/D row map (m89)
                size_t oi = ((size_t)b * GN + i) * FOUT + o;
                out[oi] = S < 0.0 ? 1.0f : 0.0f;
                if (fabs(S) <= 2048.0) {
                    unsigned int idx = atomicAdd(&nflag, 1u);
                    if (idx < 128) flagbuf[idx] = ((unsigned int)i << 6) | (unsigned int)o;
                }
            }
        }
    }

    // ---- in-block exact fixup (expected ~0.2 items/block) ----
    __syncthreads();
    unsigned int nf = nflag;
    if (nf > 128) nf = 128;
    for (unsigned int f = 0; f < nf; ++f) {
        unsigned int e = flagbuf[f];
        int o = e & 63;
        int i = (int)(e >> 6);
        int row16 = i & 15, r = (i >> 4) & 3;
        int s = tid >> 3, lg = (tid >> 1) & 3, hf = tid & 1;
        unsigned long long w = tmask[((size_t)rt * 64 + s) * 64 + (lg * 16 + row16)];
        double ps = 0.0;
        const double* hwc = hW + ((size_t)b * GN + s * 64 + lg * 16) * FOUT + o;
#pragma unroll
        for (int jj = hf * 8; jj < hf * 8 + 8; ++jj) {
            if ((w >> (r * 16 + jj)) & 1ull)
                ps += hwc[(size_t)jj * FOUT];
        }
#pragma unroll
        for (int d = 32; d >= 1; d >>= 1) ps += __shfl_down(ps, d, 64);
        if (lane == 0) fred[wv] = ps;
        __syncthreads();
        if (tid == 0) {
            double tot = ((fred[0] + fred[1]) + (fred[2] + fred[3]))
                       + ((fred[4] + fred[5]) + (fred[6] + fred[7]));
            out[((size_t)b * GN + i) * FOUT + o] = tot < 0.0 ? 1.0f : 0.0f;
        }
        __syncthreads();
    }
}

extern "C" void kernel_launch(void* const* d_in, const int* in_sizes, int n_in,
                              void* d_out, int out_size, void* d_ws, size_t ws_size,
                              hipStream_t stream) {
    const float* h   = (const float*)d_in[0];   // [4,4096,128]
    const int*   adj = (const int*)d_in[1];     // [4096,4096]
    const float* W   = (const float*)d_in[2];   // [128,64]
    float* out = (float*)d_out;                 // [4,4096,64] f32

    char* ws = (char*)d_ws;
    double* hW                = (double*)ws;                          // 8 MB @ 0
    unsigned char* Bp         = (unsigned char*)(ws + 8388608);       // 3 MB @ 8M
    unsigned long long* tmask = (unsigned long long*)(ws + 12582912); // 2 MB @ 12M

    pack_kernel<<<256, 1024, 0, stream>>>(adj, tmask);
    hwrepack_kernel<<<1024, 256, 0, stream>>>(h, W, hW, Bp);
    gemm_kernel<<<256, 512, 0, stream>>>(Bp, tmask, hW, out);
}